// Round 7
// baseline (429.585 us; speedup 1.0000x reference)
//
#include <hip/hip_runtime.h>
#include <hip/hip_bf16.h>
#include <stdint.h>

typedef __hip_bfloat16 bf16;
typedef __bf16 bf16x8 __attribute__((ext_vector_type(8)));
typedef float floatx4 __attribute__((ext_vector_type(4)));

#define MFMA16(a, b, c) __builtin_amdgcn_mfma_f32_16x16x32_bf16((a), (b), (c), 0, 0, 0)

typedef __attribute__((address_space(3))) uint32_t lds_u32;
typedef const __attribute__((address_space(1))) uint32_t gbl_u32;

__device__ __forceinline__ void async16(const void* g, void* s) {
    __builtin_amdgcn_global_load_lds((gbl_u32*)g, (lds_u32*)s, 16, 0, 0);
}

// fp32 -> bf16 RNE (scalar)
__device__ __forceinline__ unsigned short f2bf_rne(float f) {
    union { float f; unsigned u; } v; v.f = f;
    const unsigned u = v.u;
    return (unsigned short)((u + 0x7FFFu + ((u >> 16) & 1u)) >> 16);
}
// packed pair: v_cvt_pk_bf16_f32 on gfx950 (falls back safely otherwise)
__device__ __forceinline__ unsigned pk2(float a, float b) {
    __hip_bfloat162 h = __float22bfloat162_rn(make_float2(a, b));
    return *(unsigned*)&h;
}

// ---------------------------------------------------------------------------
// arena element offsets: X 8M | Wq 1M | Wk 1M | Wv 1M | Wo 1M  (bf16)
// ---------------------------------------------------------------------------
#define A_X   0L
#define A_WQ  8388608L
#define A_WK  9437184L
#define A_WV  10485760L
#define A_WO  11534336L
#define A_END 12582912L

__global__ __launch_bounds__(256) void cvt5(
    const float* __restrict__ s0, const float* __restrict__ s1,
    const float* __restrict__ s2, const float* __restrict__ s3,
    const float* __restrict__ s4, unsigned short* __restrict__ dst)
{
    const long beg[6] = {A_X, A_WQ, A_WK, A_WV, A_WO, A_END};
    const float* srcs[5] = {s0, s1, s2, s3, s4};
    const long nchunk = A_END / 8;
    for (long c = (long)blockIdx.x * 256 + threadIdx.x; c < nchunk;
         c += (long)gridDim.x * 256) {
        const long off = c * 8;
        int s = 0;
#pragma unroll
        for (int i = 1; i < 5; ++i) if (off >= beg[i]) s = i;
        const float* sp = srcs[s] + (off - beg[s]);
        const uint4 lo = *(const uint4*)(sp);
        const uint4 hi = *(const uint4*)(sp + 4);
        const float* fl = (const float*)&lo;
        const float* fh = (const float*)&hi;
        uint4 o;
        o.x = pk2(fl[0], fl[1]); o.y = pk2(fl[2], fl[3]);
        o.z = pk2(fh[0], fh[1]); o.w = pk2(fh[2], fh[3]);
        *(uint4*)(dst + off) = o;
    }
}

// ---------------------------------------------------------------------------
// GEMM (m97 structure, validated R4-R6): C = A W^T + b
// TRANSV: the which==2 output (V) is written transposed as VT[b][h][d][key]
// (key contiguous, d stride 2048) so attention can stage V^T with dwordx4.
// ---------------------------------------------------------------------------
template <int CFP32, int TRANSV>
__global__ __launch_bounds__(256, 2) void gemm_bt3(
    const bf16* __restrict__ A,
    const bf16* __restrict__ W0, const bf16* __restrict__ W1, const bf16* __restrict__ W2,
    const float* __restrict__ b0, const float* __restrict__ b1, const float* __restrict__ b2,
    void* __restrict__ C0, void* __restrict__ C1, void* __restrict__ C2)
{
    __shared__ bf16 As[128 * 64];
    __shared__ bf16 Bs[128 * 64];

    const int tid = threadIdx.x;
    const int which = blockIdx.y >> 3;
    const int nt = blockIdx.y & 7;
    const bf16* __restrict__ W   = (which == 0) ? W0 : ((which == 1) ? W1 : W2);
    const float* __restrict__ bb = (which == 0) ? b0 : ((which == 1) ? b1 : b2);
    void* __restrict__ C         = (which == 0) ? C0 : ((which == 1) ? C1 : C2);

    const int m0 = blockIdx.x * 128;
    const int n0 = nt * 128;

    const int w  = tid >> 6;
    const int l  = tid & 63;
    const int lr = l & 15;
    const int q  = l >> 4;
    const int wm = (w & 1) * 64;
    const int wn = (w >> 1) * 64;
    const int wbase = tid & 0xC0;

    floatx4 acc[4][4];
#pragma unroll
    for (int i = 0; i < 4; ++i)
#pragma unroll
        for (int j = 0; j < 4; ++j)
            acc[i][j] = (floatx4){0.f, 0.f, 0.f, 0.f};

#pragma unroll 1
    for (int kt = 0; kt < 16; ++kt) {
        __syncthreads();
#pragma unroll
        for (int r = 0; r < 4; ++r) {
            const int u   = r * 256 + tid;
            const int row = u >> 3;
            const int kg  = u & 7;
            const int kgg = kg ^ (row & 7);
            const size_t goffA = (size_t)(m0 + row) * 1024 + kt * 64 + kgg * 8;
            const size_t goffB = (size_t)(n0 + row) * 1024 + kt * 64 + kgg * 8;
            bf16* dA = As + (size_t)(r * 256 + wbase) * 8;
            bf16* dB = Bs + (size_t)(r * 256 + wbase) * 8;
            async16(A + goffA, dA);
            async16(W + goffB, dB);
        }
        asm volatile("s_waitcnt vmcnt(0)" ::: "memory");
        __syncthreads();

#pragma unroll
        for (int ks = 0; ks < 2; ++ks) {
            bf16x8 av[4], bv[4];
#pragma unroll
            for (int i = 0; i < 4; ++i) {
                const int row = wm + i * 16 + lr;
                const int kg  = (ks * 4 + q) ^ (row & 7);
                av[i] = *(const bf16x8*)(As + row * 64 + kg * 8);
            }
#pragma unroll
            for (int j = 0; j < 4; ++j) {
                const int row = wn + j * 16 + lr;
                const int kg  = (ks * 4 + q) ^ (row & 7);
                bv[j] = *(const bf16x8*)(Bs + row * 64 + kg * 8);
            }
#pragma unroll
            for (int i = 0; i < 4; ++i)
#pragma unroll
                for (int j = 0; j < 4; ++j)
                    acc[i][j] = MFMA16(av[i], bv[j], acc[i][j]);
        }
    }

    if (TRANSV && which == 2) {
        // V transposed store: col -> (h = col>>6, d = col&63);
        // row -> (b = row>>11, key = row&2047); tile never spans b (128 | 2048).
#pragma unroll
        for (int j = 0; j < 4; ++j) {
            const int col = n0 + wn + j * 16 + lr;
            const float bj = bb[col];
            const int h = col >> 6, d = col & 63;
#pragma unroll
            for (int i = 0; i < 4; ++i) {
                const int row0 = m0 + wm + i * 16 + q * 4;   // r = 0..3 contiguous keys
                const int b = row0 >> 11;
                const int key = row0 & 2047;
                uint2 ov;
                ov.x = pk2(acc[i][j][0] + bj, acc[i][j][1] + bj);
                ov.y = pk2(acc[i][j][2] + bj, acc[i][j][3] + bj);
                *(uint2*)((unsigned short*)C +
                          ((size_t)(b * 16 + h) * 64 + d) * 2048 + key) = ov;
            }
        }
    } else {
#pragma unroll
        for (int j = 0; j < 4; ++j) {
            const int col = n0 + wn + j * 16 + lr;
            const float bj = bb[col];
#pragma unroll
            for (int i = 0; i < 4; ++i) {
#pragma unroll
                for (int r = 0; r < 4; ++r) {
                    const int row = m0 + wm + i * 16 + q * 4 + r;
                    const float val = acc[i][j][r] + bj;
                    if (CFP32)
                        ((float*)C)[(long)row * 1024 + col] = val;
                    else
                        ((unsigned short*)C)[(long)row * 1024 + col] = f2bf_rne(val);
                }
            }
        }
    }
}

// ---------------------------------------------------------------------------
// Flash attention, S^T formulation (validated R6).
// Q,K: [4,2048,16,64] bf16; VT: [b][h][d][key] bf16 (pre-transposed by GEMM).
// R7: single-buffered K/V (LDS 32KB -> 4 blocks/CU, kills 4-over-3 tail),
//     V staged via 2 dwordx4 row loads (was 16 scalar u16 column loads),
//     packed v_cvt_pk_bf16_f32 for P/O stores.
// ---------------------------------------------------------------------------
__global__ __launch_bounds__(256, 4) void attn_flash(
    const bf16* __restrict__ Q, const bf16* __restrict__ K, const bf16* __restrict__ VT,
    bf16* __restrict__ AO)
{
    __shared__ bf16 Ks[64 * 64];
    __shared__ bf16 Vt[64 * 64];   // Vt[d][key]
    __shared__ bf16 Ps[128 * 64];  // P[qrow][key], octet-swizzled

    const int tid = threadIdx.x;
    const int b = blockIdx.y >> 4, h = blockIdx.y & 15;
    const int q0 = blockIdx.x * 128;
    const size_t base = ((size_t)b * 2048) * 1024 + (size_t)h * 64;
    const size_t vtb  = (size_t)(b * 16 + h) * 64 * 2048;

    const int w  = tid >> 6;
    const int l  = tid & 63;
    const int lr = l & 15;
    const int q  = l >> 4;

    const int krow = tid >> 3, kkg = tid & 7;   // K staging: rows krow, 32+krow
    const int vd = tid >> 2,   vko = tid & 3;   // V staging: row d, key octets

    // Q fragments in registers (reused all 32 iterations): B-frag layout
    bf16x8 qb[2][2];
#pragma unroll
    for (int i = 0; i < 2; ++i)
#pragma unroll
        for (int ks = 0; ks < 2; ++ks)
            qb[i][ks] = *(const bf16x8*)(Q + base +
                (size_t)(q0 + w * 32 + i * 16 + lr) * 1024 + ks * 32 + q * 8);

    // prefetch tile 0 into registers
    uint4 kreg0 = *(const uint4*)(K + base + (size_t)krow * 1024 + kkg * 8);
    uint4 kreg1 = *(const uint4*)(K + base + (size_t)(32 + krow) * 1024 + kkg * 8);
    uint4 vreg0 = *(const uint4*)(VT + vtb + (size_t)vd * 2048 + vko * 8);
    uint4 vreg1 = *(const uint4*)(VT + vtb + (size_t)vd * 2048 + 32 + vko * 8);

    floatx4 O[2][4];
#pragma unroll
    for (int i = 0; i < 2; ++i)
#pragma unroll
        for (int d = 0; d < 4; ++d) O[i][d] = (floatx4){0.f, 0.f, 0.f, 0.f};
    float mprev[2] = {-1e30f, -1e30f}, lsum[2] = {0.f, 0.f};
    const float cs = 0.18033688011112042f;  // log2(e)/sqrt(64)

#pragma unroll 1
    for (int kt = 0; kt < 32; ++kt) {
        if (kt) __syncthreads();   // all waves done reading previous tile

        // stage prefetched tile (XOR-octet swizzle, pitch 64)
        *(uint4*)(Ks + krow * 64 + ((kkg ^ (krow & 7)) * 8))        = kreg0;
        *(uint4*)(Ks + (32 + krow) * 64 + ((kkg ^ (krow & 7)) * 8)) = kreg1;
        *(uint4*)(Vt + vd * 64 + ((vko ^ (vd & 7)) * 8))            = vreg0;
        *(uint4*)(Vt + vd * 64 + (((4 + vko) ^ (vd & 7)) * 8))      = vreg1;
        __syncthreads();

        // prefetch next tile (drains during this iteration's compute)
        if (kt < 31) {
            const size_t kb = base + (size_t)((kt + 1) * 64) * 1024;
            kreg0 = *(const uint4*)(K + kb + (size_t)krow * 1024 + kkg * 8);
            kreg1 = *(const uint4*)(K + kb + (size_t)(32 + krow) * 1024 + kkg * 8);
            const size_t vb2 = vtb + (size_t)vd * 2048 + (kt + 1) * 64;
            vreg0 = *(const uint4*)(VT + vb2 + vko * 8);
            vreg1 = *(const uint4*)(VT + vb2 + 32 + vko * 8);
        }

        // S^T = K Q^T : lane holds col=qrow(lr), row=key(q*4+r), tile 16t
        floatx4 s[2][4];
#pragma unroll
        for (int i = 0; i < 2; ++i)
#pragma unroll
            for (int t = 0; t < 4; ++t)
                s[i][t] = (floatx4){0.f, 0.f, 0.f, 0.f};
#pragma unroll
        for (int ks = 0; ks < 2; ++ks) {
            bf16x8 kb[4];
#pragma unroll
            for (int t = 0; t < 4; ++t) {
                const int R = t * 16 + lr;
                kb[t] = *(const bf16x8*)(Ks + R * 64 + (((ks * 4 + q) ^ (R & 7)) * 8));
            }
#pragma unroll
            for (int i = 0; i < 2; ++i)
#pragma unroll
                for (int t = 0; t < 4; ++t)
                    s[i][t] = MFMA16(kb[t], qb[i][ks], s[i][t]);
        }

        // online softmax: one qrow per lane per i
#pragma unroll
        for (int i = 0; i < 2; ++i) {
            float vm = fmaxf(fmaxf(s[i][0][0], s[i][0][1]), fmaxf(s[i][0][2], s[i][0][3]));
#pragma unroll
            for (int t = 1; t < 4; ++t)
                vm = fmaxf(vm, fmaxf(fmaxf(s[i][t][0], s[i][t][1]),
                                     fmaxf(s[i][t][2], s[i][t][3])));
            vm = fmaxf(vm, __shfl_xor(vm, 16));
            vm = fmaxf(vm, __shfl_xor(vm, 32));
            const float mnew  = fmaxf(mprev[i], vm * cs);
            const float alpha = exp2f(mprev[i] - mnew);
            mprev[i] = mnew;
            float rsum = 0.f;
#pragma unroll
            for (int t = 0; t < 4; ++t)
#pragma unroll
                for (int r = 0; r < 4; ++r) {
                    const float p = exp2f(s[i][t][r] * cs - mnew);
                    s[i][t][r] = p;
                    rsum += p;
                }
            rsum += __shfl_xor(rsum, 16);
            rsum += __shfl_xor(rsum, 32);
            lsum[i] = lsum[i] * alpha + rsum;
#pragma unroll
            for (int d = 0; d < 4; ++d) O[i][d] *= alpha;

            // P -> Ps[qrow][key] (packed b64 stores, swizzled octets)
            const int R = w * 32 + i * 16 + lr;
#pragma unroll
            for (int t = 0; t < 4; ++t) {
                uint2 ph;
                ph.x = pk2(s[i][t][0], s[i][t][1]);
                ph.y = pk2(s[i][t][2], s[i][t][3]);
                *(uint2*)((unsigned short*)Ps + R * 64 +
                          (((2 * t + (q >> 1)) ^ (R & 7)) * 8) + (q & 1) * 4) = ph;
            }
        }
        asm volatile("s_waitcnt lgkmcnt(0)" ::: "memory");

        // O^T += V^T P^T : A = Vt frag, B = Ps frag (own wave's rows)
#pragma unroll
        for (int kc = 0; kc < 2; ++kc) {
            bf16x8 va[4], pb[2];
#pragma unroll
            for (int dt = 0; dt < 4; ++dt) {
                const int R = dt * 16 + lr;
                va[dt] = *(const bf16x8*)(Vt + R * 64 + (((kc * 4 + q) ^ (R & 7)) * 8));
            }
#pragma unroll
            for (int i = 0; i < 2; ++i) {
                const int R = w * 32 + i * 16 + lr;
                pb[i] = *(const bf16x8*)(Ps + R * 64 + (((kc * 4 + q) ^ (R & 7)) * 8));
            }
#pragma unroll
            for (int i = 0; i < 2; ++i)
#pragma unroll
                for (int dt = 0; dt < 4; ++dt)
                    O[i][dt] = MFMA16(va[dt], pb[i], O[i][dt]);
        }
    }

    // epilogue: lane holds qrow = q0+w*32+i*16+lr, d = dt*16+q*4+r
#pragma unroll
    for (int i = 0; i < 2; ++i) {
        const float inv = 1.f / lsum[i];
        const int row = q0 + w * 32 + i * 16 + lr;
#pragma unroll
        for (int dt = 0; dt < 4; ++dt) {
            uint2 oh;
            oh.x = pk2(O[i][dt][0] * inv, O[i][dt][1] * inv);
            oh.y = pk2(O[i][dt][2] * inv, O[i][dt][3] * inv);
            *(uint2*)((unsigned short*)AO + base + (size_t)row * 1024 +
                      dt * 16 + q * 4) = oh;
        }
    }
}

extern "C" void kernel_launch(void* const* d_in, const int* in_sizes, int n_in,
                              void* d_out, int out_size, void* d_ws, size_t ws_size,
                              hipStream_t stream) {
    (void)in_sizes; (void)n_in; (void)out_size; (void)ws_size;
    const float* X  = (const float*)d_in[0];
    const float* Wq = (const float*)d_in[1];
    const float* bq = (const float*)d_in[2];
    const float* Wk = (const float*)d_in[3];
    const float* bk = (const float*)d_in[4];
    const float* Wv = (const float*)d_in[5];
    const float* bv = (const float*)d_in[6];
    const float* Wo = (const float*)d_in[7];
    const float* bo = (const float*)d_in[8];
    float* out = (float*)d_out;

    unsigned short* arena = (unsigned short*)d_ws;
    bf16* Xb  = (bf16*)(arena + A_X);
    bf16* Wqb = (bf16*)(arena + A_WQ);
    bf16* Wkb = (bf16*)(arena + A_WK);
    bf16* Wvb = (bf16*)(arena + A_WV);
    bf16* Wob = (bf16*)(arena + A_WO);

    const size_t SZ = (size_t)8192 * 1024;
    bf16* Qb  = (bf16*)(arena + A_END);
    bf16* Kb  = Qb + SZ;
    bf16* VTb = Kb + SZ;      // V stored transposed [b][h][d][key]
    bf16* AOb = VTb + SZ;

    cvt5<<<dim3(1536), dim3(256), 0, stream>>>(X, Wq, Wk, Wv, Wo, arena);

    // QKV projection; V written pre-transposed for attention
    gemm_bt3<0, 1><<<dim3(64, 24), dim3(256), 0, stream>>>(
        Xb, Wqb, Wkb, Wvb, bq, bk, bv, (void*)Qb, (void*)Kb, (void*)VTb);

    attn_flash<<<dim3(16, 64), dim3(256), 0, stream>>>(Qb, Kb, VTb, AOb);

    gemm_bt3<1, 0><<<dim3(64, 8), dim3(256), 0, stream>>>(
        AOb, Wob, Wob, Wob, bo, bo, bo, (void*)out, (void*)out, (void*)out);
}

// Round 8
// 310.338 us; speedup vs baseline: 1.3842x; 1.3842x over previous
//
#include <hip/hip_runtime.h>
#include <hip/hip_bf16.h>
#include <stdint.h>

typedef __hip_bfloat16 bf16;
typedef __bf16 bf16x8 __attribute__((ext_vector_type(8)));
typedef float floatx4 __attribute__((ext_vector_type(4)));

#define MFMA16(a, b, c) __builtin_amdgcn_mfma_f32_16x16x32_bf16((a), (b), (c), 0, 0, 0)

typedef __attribute__((address_space(3))) uint32_t lds_u32;
typedef const __attribute__((address_space(1))) uint32_t gbl_u32;

__device__ __forceinline__ void async16(const void* g, void* s) {
    __builtin_amdgcn_global_load_lds((gbl_u32*)g, (lds_u32*)s, 16, 0, 0);
}

// fp32 -> bf16 RNE (scalar)
__device__ __forceinline__ unsigned short f2bf_rne(float f) {
    union { float f; unsigned u; } v; v.f = f;
    const unsigned u = v.u;
    return (unsigned short)((u + 0x7FFFu + ((u >> 16) & 1u)) >> 16);
}
// packed pair: v_cvt_pk_bf16_f32 on gfx950
__device__ __forceinline__ unsigned pk2(float a, float b) {
    __hip_bfloat162 h = __float22bfloat162_rn(make_float2(a, b));
    return *(unsigned*)&h;
}

// ---------------------------------------------------------------------------
// arena element offsets: X 8M | Wq 1M | Wk 1M | Wv 1M | Wo 1M  (bf16)
// ---------------------------------------------------------------------------
#define A_X   0L
#define A_WQ  8388608L
#define A_WK  9437184L
#define A_WV  10485760L
#define A_WO  11534336L
#define A_END 12582912L

__global__ __launch_bounds__(256) void cvt5(
    const float* __restrict__ s0, const float* __restrict__ s1,
    const float* __restrict__ s2, const float* __restrict__ s3,
    const float* __restrict__ s4, unsigned short* __restrict__ dst)
{
    const long beg[6] = {A_X, A_WQ, A_WK, A_WV, A_WO, A_END};
    const float* srcs[5] = {s0, s1, s2, s3, s4};
    const long nchunk = A_END / 8;
    for (long c = (long)blockIdx.x * 256 + threadIdx.x; c < nchunk;
         c += (long)gridDim.x * 256) {
        const long off = c * 8;
        int s = 0;
#pragma unroll
        for (int i = 1; i < 5; ++i) if (off >= beg[i]) s = i;
        const float* sp = srcs[s] + (off - beg[s]);
        const uint4 lo = *(const uint4*)(sp);
        const uint4 hi = *(const uint4*)(sp + 4);
        const float* fl = (const float*)&lo;
        const float* fh = (const float*)&hi;
        uint4 o;
        o.x = pk2(fl[0], fl[1]); o.y = pk2(fl[2], fl[3]);
        o.z = pk2(fh[0], fh[1]); o.w = pk2(fh[2], fh[3]);
        *(uint4*)(dst + off) = o;
    }
}

// ---------------------------------------------------------------------------
// GEMM (m97 structure, validated R4-R6): C = A W^T + b
// TRANSV: which==2 output (V) written transposed as VT[b][h][d][key].
// ---------------------------------------------------------------------------
template <int CFP32, int TRANSV>
__global__ __launch_bounds__(256, 2) void gemm_bt3(
    const bf16* __restrict__ A,
    const bf16* __restrict__ W0, const bf16* __restrict__ W1, const bf16* __restrict__ W2,
    const float* __restrict__ b0, const float* __restrict__ b1, const float* __restrict__ b2,
    void* __restrict__ C0, void* __restrict__ C1, void* __restrict__ C2)
{
    __shared__ bf16 As[128 * 64];
    __shared__ bf16 Bs[128 * 64];

    const int tid = threadIdx.x;
    const int which = blockIdx.y >> 3;
    const int nt = blockIdx.y & 7;
    const bf16* __restrict__ W   = (which == 0) ? W0 : ((which == 1) ? W1 : W2);
    const float* __restrict__ bb = (which == 0) ? b0 : ((which == 1) ? b1 : b2);
    void* __restrict__ C         = (which == 0) ? C0 : ((which == 1) ? C1 : C2);

    const int m0 = blockIdx.x * 128;
    const int n0 = nt * 128;

    const int w  = tid >> 6;
    const int l  = tid & 63;
    const int lr = l & 15;
    const int q  = l >> 4;
    const int wm = (w & 1) * 64;
    const int wn = (w >> 1) * 64;
    const int wbase = tid & 0xC0;

    floatx4 acc[4][4];
#pragma unroll
    for (int i = 0; i < 4; ++i)
#pragma unroll
        for (int j = 0; j < 4; ++j)
            acc[i][j] = (floatx4){0.f, 0.f, 0.f, 0.f};

#pragma unroll 1
    for (int kt = 0; kt < 16; ++kt) {
        __syncthreads();
#pragma unroll
        for (int r = 0; r < 4; ++r) {
            const int u   = r * 256 + tid;
            const int row = u >> 3;
            const int kg  = u & 7;
            const int kgg = kg ^ (row & 7);
            const size_t goffA = (size_t)(m0 + row) * 1024 + kt * 64 + kgg * 8;
            const size_t goffB = (size_t)(n0 + row) * 1024 + kt * 64 + kgg * 8;
            bf16* dA = As + (size_t)(r * 256 + wbase) * 8;
            bf16* dB = Bs + (size_t)(r * 256 + wbase) * 8;
            async16(A + goffA, dA);
            async16(W + goffB, dB);
        }
        asm volatile("s_waitcnt vmcnt(0)" ::: "memory");
        __syncthreads();

#pragma unroll
        for (int ks = 0; ks < 2; ++ks) {
            bf16x8 av[4], bv[4];
#pragma unroll
            for (int i = 0; i < 4; ++i) {
                const int row = wm + i * 16 + lr;
                const int kg  = (ks * 4 + q) ^ (row & 7);
                av[i] = *(const bf16x8*)(As + row * 64 + kg * 8);
            }
#pragma unroll
            for (int j = 0; j < 4; ++j) {
                const int row = wn + j * 16 + lr;
                const int kg  = (ks * 4 + q) ^ (row & 7);
                bv[j] = *(const bf16x8*)(Bs + row * 64 + kg * 8);
            }
#pragma unroll
            for (int i = 0; i < 4; ++i)
#pragma unroll
                for (int j = 0; j < 4; ++j)
                    acc[i][j] = MFMA16(av[i], bv[j], acc[i][j]);
        }
    }

    if (TRANSV && which == 2) {
        // V transposed store: col -> (h, d); row -> (b, key); 4 keys packed.
#pragma unroll
        for (int j = 0; j < 4; ++j) {
            const int col = n0 + wn + j * 16 + lr;
            const float bj = bb[col];
            const int h = col >> 6, d = col & 63;
#pragma unroll
            for (int i = 0; i < 4; ++i) {
                const int row0 = m0 + wm + i * 16 + q * 4;
                const int b = row0 >> 11;
                const int key = row0 & 2047;
                uint2 ov;
                ov.x = pk2(acc[i][j][0] + bj, acc[i][j][1] + bj);
                ov.y = pk2(acc[i][j][2] + bj, acc[i][j][3] + bj);
                *(uint2*)((unsigned short*)C +
                          ((size_t)(b * 16 + h) * 64 + d) * 2048 + key) = ov;
            }
        }
    } else {
#pragma unroll
        for (int j = 0; j < 4; ++j) {
            const int col = n0 + wn + j * 16 + lr;
            const float bj = bb[col];
#pragma unroll
            for (int i = 0; i < 4; ++i) {
#pragma unroll
                for (int r = 0; r < 4; ++r) {
                    const int row = m0 + wm + i * 16 + q * 4 + r;
                    const float val = acc[i][j][r] + bj;
                    if (CFP32)
                        ((float*)C)[(long)row * 1024 + col] = val;
                    else
                        ((unsigned short*)C)[(long)row * 1024 + col] = f2bf_rne(val);
                }
            }
        }
    }
}

// ---------------------------------------------------------------------------
// Flash attention, S^T formulation (validated R6).
// R8: launch_bounds (256,2) -- R7's (256,4) made the allocator target
// 8 waves/EU (VGPR=64) and spill ~540 MB of scratch (WRITE_SIZE blowup).
// With cap=256 it allocates ~105 naturally; HW occupancy self-selects
// 4 blocks/CU (VGPR) since LDS is 32 KB.
// ---------------------------------------------------------------------------
__global__ __launch_bounds__(256, 2) void attn_flash(
    const bf16* __restrict__ Q, const bf16* __restrict__ K, const bf16* __restrict__ VT,
    bf16* __restrict__ AO)
{
    __shared__ bf16 Ks[64 * 64];
    __shared__ bf16 Vt[64 * 64];   // Vt[d][key]
    __shared__ bf16 Ps[128 * 64];  // P[qrow][key], octet-swizzled

    const int tid = threadIdx.x;
    const int b = blockIdx.y >> 4, h = blockIdx.y & 15;
    const int q0 = blockIdx.x * 128;
    const size_t base = ((size_t)b * 2048) * 1024 + (size_t)h * 64;
    const size_t vtb  = (size_t)(b * 16 + h) * 64 * 2048;

    const int w  = tid >> 6;
    const int l  = tid & 63;
    const int lr = l & 15;
    const int q  = l >> 4;

    const int krow = tid >> 3, kkg = tid & 7;   // K staging: rows krow, 32+krow
    const int vd = tid >> 2,   vko = tid & 3;   // V staging: row d, key octets

    // Q fragments in registers (reused all 32 iterations): B-frag layout
    bf16x8 qb[2][2];
#pragma unroll
    for (int i = 0; i < 2; ++i)
#pragma unroll
        for (int ks = 0; ks < 2; ++ks)
            qb[i][ks] = *(const bf16x8*)(Q + base +
                (size_t)(q0 + w * 32 + i * 16 + lr) * 1024 + ks * 32 + q * 8);

    // prefetch tile 0 into registers
    uint4 kreg0 = *(const uint4*)(K + base + (size_t)krow * 1024 + kkg * 8);
    uint4 kreg1 = *(const uint4*)(K + base + (size_t)(32 + krow) * 1024 + kkg * 8);
    uint4 vreg0 = *(const uint4*)(VT + vtb + (size_t)vd * 2048 + vko * 8);
    uint4 vreg1 = *(const uint4*)(VT + vtb + (size_t)vd * 2048 + 32 + vko * 8);

    floatx4 O[2][4];
#pragma unroll
    for (int i = 0; i < 2; ++i)
#pragma unroll
        for (int d = 0; d < 4; ++d) O[i][d] = (floatx4){0.f, 0.f, 0.f, 0.f};
    float mprev[2] = {-1e30f, -1e30f}, lsum[2] = {0.f, 0.f};
    const float cs = 0.18033688011112042f;  // log2(e)/sqrt(64)

#pragma unroll 1
    for (int kt = 0; kt < 32; ++kt) {
        if (kt) __syncthreads();   // all waves done reading previous tile

        // stage prefetched tile (XOR-octet swizzle, pitch 64)
        *(uint4*)(Ks + krow * 64 + ((kkg ^ (krow & 7)) * 8))        = kreg0;
        *(uint4*)(Ks + (32 + krow) * 64 + ((kkg ^ (krow & 7)) * 8)) = kreg1;
        *(uint4*)(Vt + vd * 64 + ((vko ^ (vd & 7)) * 8))            = vreg0;
        *(uint4*)(Vt + vd * 64 + (((4 + vko) ^ (vd & 7)) * 8))      = vreg1;
        __syncthreads();

        // prefetch next tile (drains during this iteration's compute)
        if (kt < 31) {
            const size_t kb = base + (size_t)((kt + 1) * 64) * 1024;
            kreg0 = *(const uint4*)(K + kb + (size_t)krow * 1024 + kkg * 8);
            kreg1 = *(const uint4*)(K + kb + (size_t)(32 + krow) * 1024 + kkg * 8);
            const size_t vb2 = vtb + (size_t)vd * 2048 + (kt + 1) * 64;
            vreg0 = *(const uint4*)(VT + vb2 + vko * 8);
            vreg1 = *(const uint4*)(VT + vb2 + 32 + vko * 8);
        }

        // S^T = K Q^T : lane holds col=qrow(lr), row=key(q*4+r), tile 16t
        floatx4 s[2][4];
#pragma unroll
        for (int i = 0; i < 2; ++i)
#pragma unroll
            for (int t = 0; t < 4; ++t)
                s[i][t] = (floatx4){0.f, 0.f, 0.f, 0.f};
#pragma unroll
        for (int ks = 0; ks < 2; ++ks) {
            bf16x8 kb[4];
#pragma unroll
            for (int t = 0; t < 4; ++t) {
                const int R = t * 16 + lr;
                kb[t] = *(const bf16x8*)(Ks + R * 64 + (((ks * 4 + q) ^ (R & 7)) * 8));
            }
#pragma unroll
            for (int i = 0; i < 2; ++i)
#pragma unroll
                for (int t = 0; t < 4; ++t)
                    s[i][t] = MFMA16(kb[t], qb[i][ks], s[i][t]);
        }

        // online softmax: one qrow per lane per i
#pragma unroll
        for (int i = 0; i < 2; ++i) {
            float vm = fmaxf(fmaxf(s[i][0][0], s[i][0][1]), fmaxf(s[i][0][2], s[i][0][3]));
#pragma unroll
            for (int t = 1; t < 4; ++t)
                vm = fmaxf(vm, fmaxf(fmaxf(s[i][t][0], s[i][t][1]),
                                     fmaxf(s[i][t][2], s[i][t][3])));
            vm = fmaxf(vm, __shfl_xor(vm, 16));
            vm = fmaxf(vm, __shfl_xor(vm, 32));
            const float mnew  = fmaxf(mprev[i], vm * cs);
            const float alpha = exp2f(mprev[i] - mnew);
            mprev[i] = mnew;
            float rsum = 0.f;
#pragma unroll
            for (int t = 0; t < 4; ++t)
#pragma unroll
                for (int r = 0; r < 4; ++r) {
                    const float p = exp2f(s[i][t][r] * cs - mnew);
                    s[i][t][r] = p;
                    rsum += p;
                }
            rsum += __shfl_xor(rsum, 16);
            rsum += __shfl_xor(rsum, 32);
            lsum[i] = lsum[i] * alpha + rsum;
#pragma unroll
            for (int d = 0; d < 4; ++d) O[i][d] *= alpha;

            // P -> Ps[qrow][key] (packed b64 stores, swizzled octets)
            const int R = w * 32 + i * 16 + lr;
#pragma unroll
            for (int t = 0; t < 4; ++t) {
                uint2 ph;
                ph.x = pk2(s[i][t][0], s[i][t][1]);
                ph.y = pk2(s[i][t][2], s[i][t][3]);
                *(uint2*)((unsigned short*)Ps + R * 64 +
                          (((2 * t + (q >> 1)) ^ (R & 7)) * 8) + (q & 1) * 4) = ph;
            }
        }
        asm volatile("s_waitcnt lgkmcnt(0)" ::: "memory");

        // O^T += V^T P^T : A = Vt frag, B = Ps frag (own wave's rows)
#pragma unroll
        for (int kc = 0; kc < 2; ++kc) {
            bf16x8 va[4], pb[2];
#pragma unroll
            for (int dt = 0; dt < 4; ++dt) {
                const int R = dt * 16 + lr;
                va[dt] = *(const bf16x8*)(Vt + R * 64 + (((kc * 4 + q) ^ (R & 7)) * 8));
            }
#pragma unroll
            for (int i = 0; i < 2; ++i) {
                const int R = w * 32 + i * 16 + lr;
                pb[i] = *(const bf16x8*)(Ps + R * 64 + (((kc * 4 + q) ^ (R & 7)) * 8));
            }
#pragma unroll
            for (int i = 0; i < 2; ++i)
#pragma unroll
                for (int dt = 0; dt < 4; ++dt)
                    O[i][dt] = MFMA16(va[dt], pb[i], O[i][dt]);
        }
    }

    // epilogue: lane holds qrow = q0+w*32+i*16+lr, d = dt*16+q*4+r
#pragma unroll
    for (int i = 0; i < 2; ++i) {
        const float inv = 1.f / lsum[i];
        const int row = q0 + w * 32 + i * 16 + lr;
#pragma unroll
        for (int dt = 0; dt < 4; ++dt) {
            uint2 oh;
            oh.x = pk2(O[i][dt][0] * inv, O[i][dt][1] * inv);
            oh.y = pk2(O[i][dt][2] * inv, O[i][dt][3] * inv);
            *(uint2*)((unsigned short*)AO + base + (size_t)row * 1024 +
                      dt * 16 + q * 4) = oh;
        }
    }
}

extern "C" void kernel_launch(void* const* d_in, const int* in_sizes, int n_in,
                              void* d_out, int out_size, void* d_ws, size_t ws_size,
                              hipStream_t stream) {
    (void)in_sizes; (void)n_in; (void)out_size; (void)ws_size;
    const float* X  = (const float*)d_in[0];
    const float* Wq = (const float*)d_in[1];
    const float* bq = (const float*)d_in[2];
    const float* Wk = (const float*)d_in[3];
    const float* bk = (const float*)d_in[4];
    const float* Wv = (const float*)d_in[5];
    const float* bv = (const float*)d_in[6];
    const float* Wo = (const float*)d_in[7];
    const float* bo = (const float*)d_in[8];
    float* out = (float*)d_out;

    unsigned short* arena = (unsigned short*)d_ws;
    bf16* Xb  = (bf16*)(arena + A_X);
    bf16* Wqb = (bf16*)(arena + A_WQ);
    bf16* Wkb = (bf16*)(arena + A_WK);
    bf16* Wvb = (bf16*)(arena + A_WV);
    bf16* Wob = (bf16*)(arena + A_WO);

    const size_t SZ = (size_t)8192 * 1024;
    bf16* Qb  = (bf16*)(arena + A_END);
    bf16* Kb  = Qb + SZ;
    bf16* VTb = Kb + SZ;      // V stored transposed [b][h][d][key]
    bf16* AOb = VTb + SZ;

    cvt5<<<dim3(1536), dim3(256), 0, stream>>>(X, Wq, Wk, Wv, Wo, arena);

    gemm_bt3<0, 1><<<dim3(64, 24), dim3(256), 0, stream>>>(
        Xb, Wqb, Wkb, Wvb, bq, bk, bv, (void*)Qb, (void*)Kb, (void*)VTb);

    attn_flash<<<dim3(16, 64), dim3(256), 0, stream>>>(Qb, Kb, VTb, AOb);

    gemm_bt3<1, 0><<<dim3(64, 8), dim3(256), 0, stream>>>(
        AOb, Wob, Wob, Wob, bo, bo, bo, (void*)out, (void*)out, (void*)out);
}